// Round 4
// baseline (652.403 us; speedup 1.0000x reference)
//
#include <hip/hip_runtime.h>

// BilateralFilter: 8 x 1024 x 1024 x 3 fp32, D=9 (radius 4), sigma_color =
// sigma_space = 75, reflect padding, taps with dy*dy+dx*dx <= 16 (49 live).
//
// Round 2 kernel, third submission (rounds 2 & 3 were broker/container infra
// failures — kernel never ran): vertical register blocking (4 outputs/thread)
// + RGBX float4 LDS tiles (one ds_read_b128 per neighbor) + per-row
// halo-width pruning + pre-scaled pixels so weight = exp2(fma(d,-d,const)).

namespace {
constexpr int Himg = 1024;
constexpr int Wimg = 1024;
constexpr int CHN  = 3;
constexpr int RAD  = 4;

constexpr int BXT   = 64;              // tile width  (one wave-row)
constexpr int PV    = 4;               // vertical outputs per thread
constexpr int WAVES = 4;               // 256 threads / block
constexpr int BYT   = PV * WAVES;      // 16 output rows / block
constexpr int TW    = BXT + 2 * RAD;   // 72 px wide (halo)
constexpr int TH    = BYT + 2 * RAD;   // 24 rows    (halo)
constexpr int NPX   = TW * TH;         // 1728 staged pixels

constexpr float LOG2E = 1.4426950408889634f;
constexpr float COEFF = -0.5f / (75.0f * 75.0f);   // sigma_color == sigma_space
constexpr float KC2   = COEFF * LOG2E;             // exp2-domain coefficient (<0)

// half-width of the neighbor strip actually needed per source row sr (0..11),
// given the r2 <= 16 tap mask and 4 consumer outputs per thread:
//   lim(|dy|) = {4,3,3,2,0};  WHALF[sr] = max_j lim(|sr-4-j|)
__device__ constexpr int WHALF[12] = {0, 2, 3, 3, 4, 4, 4, 4, 3, 3, 2, 0};
}

__device__ __forceinline__ int reflect_idx(int i, int n) {
    i = (i < 0) ? -i : i;
    return (i >= n) ? (2 * n - 2 - i) : i;
}

__global__ __launch_bounds__(256, 4)
void bilateral_kernel(const float* __restrict__ in, float* __restrict__ out) {
    __shared__ float4 tile[TH][TW];    // 24 x 72 x 16B = 27648 B

    // scale s = sqrt(-KC2): staged px are s*v, so w = exp2(fma(diff,-diff,KC2*r2))
    const float SC     = sqrtf(-KC2);      // constant-folded
    const float INV_SC = 1.0f / SC;

    const int tid = threadIdx.x;
    const int x0  = blockIdx.x * BXT;
    const int y0  = blockIdx.y * BYT;

    const float* __restrict__ img = in + (size_t)blockIdx.z * Himg * Wimg * CHN;

    // ---- stage RGBX tile (reflect halo), values pre-scaled by SC ----
    for (int i = tid; i < NPX; i += 256) {
        const int row = i / TW;
        const int px  = i - row * TW;
        const int gy  = reflect_idx(y0 - RAD + row, Himg);
        const int gx  = reflect_idx(x0 - RAD + px,  Wimg);
        const float* p = img + ((size_t)gy * Wimg + gx) * CHN;
        tile[row][px] = make_float4(p[0] * SC, p[1] * SC, p[2] * SC, 0.0f);
    }
    __syncthreads();

    // ---- each thread: 4 vertically-adjacent output pixels at column tx ----
    const int tx = tid & 63;
    const int wv = tid >> 6;
    const int ly = wv * PV;            // tile-row of this thread's first source row

    float4 c[PV];
#pragma unroll
    for (int j = 0; j < PV; ++j) c[j] = tile[ly + RAD + j][tx + RAD];

    float4 acc[PV];
#pragma unroll
    for (int j = 0; j < PV; ++j) acc[j] = make_float4(0.f, 0.f, 0.f, 0.f);

#pragma unroll
    for (int sr = 0; sr < PV + 2 * RAD; ++sr) {       // 12 source rows
        const int L = WHALF[sr];                       // compile-time after unroll
#pragma unroll
        for (int dx = -RAD; dx <= RAD; ++dx) {
            if (dx < -L || dx > L) continue;           // pruned at compile time
            const float4 nb = tile[ly + sr][tx + RAD + dx];   // ds_read_b128
#pragma unroll
            for (int j = 0; j < PV; ++j) {
                const int dy = sr - RAD - j;
                if (dy < -RAD || dy > RAD) continue;
                const int r2 = dy * dy + dx * dx;
                if (r2 > RAD * RAD) continue;          // 196 live taps/thread

                const float d0 = nb.x - c[j].x;
                const float d1 = nb.y - c[j].y;
                const float d2 = nb.z - c[j].z;
                const float diff = fabsf(d0) + fabsf(d1) + fabsf(d2);
                // w = exp2(KC2*(diff_raw^2 + r2)); diff is pre-scaled so the
                // color term is just -diff*diff (neg folds into the fma)
                const float wgt = __builtin_amdgcn_exp2f(
                    fmaf(diff, -diff, KC2 * (float)r2));

                acc[j].x = fmaf(wgt, nb.x, acc[j].x);
                acc[j].y = fmaf(wgt, nb.y, acc[j].y);
                acc[j].z = fmaf(wgt, nb.z, acc[j].z);
                acc[j].w += wgt;
            }
        }
    }

#pragma unroll
    for (int j = 0; j < PV; ++j) {
        const float inv = (1.0f / acc[j].w) * INV_SC;  // un-scale numerator
        const size_t o =
            ((size_t)(blockIdx.z * Himg + y0 + ly + j) * Wimg + (x0 + tx)) * CHN;
        out[o + 0] = acc[j].x * inv;
        out[o + 1] = acc[j].y * inv;
        out[o + 2] = acc[j].z * inv;
    }
}

extern "C" void kernel_launch(void* const* d_in, const int* in_sizes, int n_in,
                              void* d_out, int out_size, void* d_ws, size_t ws_size,
                              hipStream_t stream) {
    const float* in = (const float*)d_in[0];
    float* out = (float*)d_out;

    const int B = in_sizes[0] / (Himg * Wimg * CHN);   // = 8

    dim3 grid(Wimg / BXT, Himg / BYT, B);              // 16 x 64 x 8
    dim3 block(256);
    bilateral_kernel<<<grid, block, 0, stream>>>(in, out);
}

// Round 5
// 253.990 us; speedup vs baseline: 2.5686x; 2.5686x over previous
//
#include <hip/hip_runtime.h>

// BilateralFilter: 8 x 1024 x 1024 x 3 fp32, D=9 (radius 4), sigma_color =
// sigma_space = 75, reflect padding, taps with dy*dy+dx*dx <= 16 (49 live).
//
// Round 5: REVERT to the round-1 skeleton (1 px/thread, 9x9 unrolled nest,
// no arrays — round 4's PV=4 array version spilled to scratch: hbm_bytes
// 13x, VALUBusy 101%->23%). Keep structure, cut VALU work:
//   - float4 RGBW LDS tile: 1 ds_read_b128/tap (offset immediates) vs 3 b32
//   - W-lane staged as 1.0 => acc += nb*w does numerator AND denominator
//     (vector fma -> v_pk_fma_f32 pairs)
//   - pre-scaled pixels => weight = exp2(fma(diff,-diff,const)), 1 fma + 1 exp

namespace {
constexpr int Himg = 1024;
constexpr int Wimg = 1024;
constexpr int CHN  = 3;
constexpr int RAD  = 4;

constexpr int BXT = 64;              // tile width (one wave-row)
constexpr int BYT = 4;               // 4 waves -> 4 output rows
constexpr int TW  = BXT + 2 * RAD;   // 72 px
constexpr int TH  = BYT + 2 * RAD;   // 12 rows
constexpr int NPX = TW * TH;         // 864 staged pixels

constexpr float LOG2E = 1.4426950408889634f;
constexpr float COEFF = -0.5f / (75.0f * 75.0f);   // sigma_color == sigma_space
constexpr float KC2   = COEFF * LOG2E;             // exp2-domain coefficient (<0)

typedef float f4 __attribute__((ext_vector_type(4)));
}

__device__ __forceinline__ int reflect_idx(int i, int n) {
    i = (i < 0) ? -i : i;
    return (i >= n) ? (2 * n - 2 - i) : i;
}

__global__ __launch_bounds__(256, 4)
void bilateral_kernel(const float* __restrict__ in, float* __restrict__ out) {
    __shared__ f4 tile[TH][TW];        // 12 x 72 x 16B = 13824 B

    const float SC     = sqrtf(-KC2);  // constant-folded; staged px = SC*v
    const float INV_SC = 1.0f / SC;

    const int tid = threadIdx.x;
    const int x0  = blockIdx.x * BXT;
    const int y0  = blockIdx.y * BYT;

    const float* __restrict__ img = in + (size_t)blockIdx.z * Himg * Wimg * CHN;

    // ---- stage RGBW tile (reflect halo): (r*SC, g*SC, b*SC, 1.0) ----
    for (int i = tid; i < NPX; i += 256) {
        const int row = i / TW;
        const int px  = i - row * TW;
        const int gy  = reflect_idx(y0 - RAD + row, Himg);
        const int gx  = reflect_idx(x0 - RAD + px,  Wimg);
        const float* p = img + ((size_t)gy * Wimg + gx) * CHN;
        f4 v;
        v.x = p[0] * SC;
        v.y = p[1] * SC;
        v.z = p[2] * SC;
        v.w = 1.0f;
        tile[row][px] = v;             // ds_write_b128
    }
    __syncthreads();

    // ---- one output pixel per thread ----
    const int tx = tid & 63;           // wave = one 64-px row
    const int ty = tid >> 6;

    const f4 c = tile[ty + RAD][tx + RAD];
    const float cx = c.x, cy = c.y, cz = c.z;

    f4 acc = (f4){0.0f, 0.0f, 0.0f, 0.0f};

#pragma unroll
    for (int dy = -RAD; dy <= RAD; ++dy) {
#pragma unroll
        for (int dx = -RAD; dx <= RAD; ++dx) {
            const int r2 = dy * dy + dx * dx;
            if (r2 > RAD * RAD) continue;          // compile-time pruned (49 live)

            const f4 nb = tile[ty + RAD + dy][tx + RAD + dx];  // ds_read_b128

            // L1 color distance on pre-scaled values; abs folds into adds
            const float diff = fabsf(nb.x - cx) + fabsf(nb.y - cy)
                             + fabsf(nb.z - cz);

            // w = exp2(KC2*(diff_raw^2 + r2)) = exp2(-diff^2 + KC2*r2)
            const float w = __builtin_amdgcn_exp2f(
                fmaf(diff, -diff, KC2 * (float)r2));

            acc += nb * w;             // RGB numerator + W-lane denominator
        }
    }

    const float inv = (1.0f / acc.w) * INV_SC;     // un-scale numerator
    const size_t o =
        ((size_t)(blockIdx.z * Himg + y0 + ty) * Wimg + (x0 + tx)) * CHN;
    out[o + 0] = acc.x * inv;
    out[o + 1] = acc.y * inv;
    out[o + 2] = acc.z * inv;
}

extern "C" void kernel_launch(void* const* d_in, const int* in_sizes, int n_in,
                              void* d_out, int out_size, void* d_ws, size_t ws_size,
                              hipStream_t stream) {
    const float* in = (const float*)d_in[0];
    float* out = (float*)d_out;

    const int B = in_sizes[0] / (Himg * Wimg * CHN);   // = 8

    dim3 grid(Wimg / BXT, Himg / BYT, B);              // 16 x 256 x 8
    dim3 block(256);
    bilateral_kernel<<<grid, block, 0, stream>>>(in, out);
}